// Round 9
// baseline (277.266 us; speedup 1.0000x reference)
//
#include <hip/hip_runtime.h>

// BasicRNN R8: (a) k_step 1024 threads (16 waves/CU vs 8 — it was latency-bound at
// 1 block/CU, not L1-BW-bound: 1MB/CU = 6.8us floor vs 17us observed), 16-way K-split,
// multi-round fold reduce in 64KB LDS; (b) k_prep W-phase retiled to 64k x 128n so each
// W row is read as 512B contiguous segments (was 64B scatter, HBM 26%).
// Fragment-tiled operands:
//   elem(r,c) = frag*512 + lane*8 + (c&7), frag=(r>>5)*(C/16)+(c>>4), lane=(r&31)+32*((c>>3)&1)

typedef __bf16 bf16x8 __attribute__((ext_vector_type(8)));
typedef float  f32x16 __attribute__((ext_vector_type(16)));

#define TOTAL 4096
#define BATCH 256
#define INDIM 2048
#define SDIM  1024
#define NCLS  1000

#define MFMA(a, b, c) __builtin_amdgcn_mfma_f32_32x32x16_bf16((a), (b), (c), 0, 0, 0)

__device__ inline f32x16 zero16() {
    f32x16 v;
#pragma unroll
    for (int i = 0; i < 16; ++i) v[i] = 0.f;
    return v;
}

__device__ inline void swz_slot(const float* __restrict__ in, __bf16* __restrict__ out,
                                int C, int Rvalid, int t) {
    const int lane = t & 63;
    const int frag = t >> 6;
    const int kcN = C >> 4;
    const int rt = frag / kcN;
    const int kc = frag - rt * kcN;
    const int r = rt * 32 + (lane & 31);
    const int c = kc * 16 + (lane >> 5) * 8;
    alignas(16) __bf16 v[8];
    if (r < Rvalid) {
        const float* p = in + (size_t)r * C + c;
#pragma unroll
        for (int j = 0; j < 8; ++j) v[j] = (__bf16)p[j];
    } else {
#pragma unroll
        for (int j = 0; j < 8; ++j) v[j] = (__bf16)0.f;
    }
    *(ulonglong2*)(out + (size_t)t * 8) = *(const ulonglong2*)v;
}

// ---- merged preprocessing + E-GEMM ----
// grid 2816 x 256: [0,256) E-GEMM; [256,2304) W transpose-swizzle (64k x 128n tiles);
//                  [2304,2816) out_w swizzle
__global__ __launch_bounds__(256) void k_prep(const float* __restrict__ W,
                                              const float* __restrict__ x,
                                              const float* __restrict__ in_w,
                                              const float* __restrict__ in_b,
                                              const float* __restrict__ out_w,
                                              __bf16* __restrict__ WT,
                                              __bf16* __restrict__ OWT,
                                              float* __restrict__ Ebuf,
                                              __bf16* __restrict__ H0) {
    __shared__ float t[128][65];   // 33 KB; E path reuses as red[4][1024]
    const int bid = blockIdx.x;
    const int tid = threadIdx.x;
    if (bid < 256) {
        // ---- E = x @ in_w^T + in_b ; H0[:, :1024] = relu(E) (tiled) ----
        float* red = &t[0][0];   // 4 x 1024
        const int mt = bid >> 5, nt = bid & 31;
        const int wave = tid >> 6, lane = tid & 63;
        const int l31 = lane & 31, kh = (lane >> 5) * 8;
        const int k0 = wave * 512;
        const float* Ax = x    + (size_t)(mt * 32 + l31) * INDIM + k0 + kh;
        const float* Bw = in_w + (size_t)(nt * 32 + l31) * INDIM + k0 + kh;
        f32x16 acc = zero16();
#pragma unroll 4
        for (int i = 0; i < 32; ++i) {
            const float* pa = Ax + i * 16;
            const float* pb = Bw + i * 16;
            float4 a0 = *(const float4*)pa, a1 = *(const float4*)(pa + 4);
            float4 b0 = *(const float4*)pb, b1 = *(const float4*)(pb + 4);
            bf16x8 a, b;
            a[0] = (__bf16)a0.x; a[1] = (__bf16)a0.y; a[2] = (__bf16)a0.z; a[3] = (__bf16)a0.w;
            a[4] = (__bf16)a1.x; a[5] = (__bf16)a1.y; a[6] = (__bf16)a1.z; a[7] = (__bf16)a1.w;
            b[0] = (__bf16)b0.x; b[1] = (__bf16)b0.y; b[2] = (__bf16)b0.z; b[3] = (__bf16)b0.w;
            b[4] = (__bf16)b1.x; b[5] = (__bf16)b1.y; b[6] = (__bf16)b1.z; b[7] = (__bf16)b1.w;
            acc = MFMA(a, b, acc);
        }
#pragma unroll
        for (int r = 0; r < 16; ++r) {
            int row = (r & 3) + 8 * (r >> 2) + 4 * (lane >> 5);
            red[wave * 1024 + row * 32 + l31] = acc[r];
        }
        __syncthreads();
        const int e0 = tid * 4;
        float4 s = {0.f, 0.f, 0.f, 0.f};
#pragma unroll
        for (int w = 0; w < 4; ++w) {
            float4 v = *(const float4*)&red[w * 1024 + e0];
            s.x += v.x; s.y += v.y; s.z += v.z; s.w += v.w;
        }
        const int row = e0 >> 5, col = e0 & 31;
        const int m = mt * 32 + row, n = nt * 32 + col;
        float v[4] = {s.x + in_b[n], s.y + in_b[n + 1], s.z + in_b[n + 2], s.w + in_b[n + 3]};
        *(float4*)(Ebuf + m * SDIM + n) = *(const float4*)v;
        alignas(8) __bf16 o[4];
#pragma unroll
        for (int j = 0; j < 4; ++j) o[j] = (__bf16)fmaxf(v[j], 0.f);
        const size_t frag = (size_t)(m >> 5) * (TOTAL / 16) + (n >> 4);
        const int lh = (m & 31) + 32 * ((n >> 3) & 1);
        *(ushort4*)(H0 + frag * 512 + lh * 8 + (n & 7)) = *(const ushort4*)o;
    } else if (bid < 2304) {
        // ---- W (f32, W[k][n]) -> WT tiled bf16 (r=n, c=k); 64k x 128n tile ----
        // reads: 512B contiguous per row (2 float4/thread, 16 threads/row);
        // LDS t[n][k] stride 65 -> 4-way write alias; reads contiguous b128.
        const int wb = bid - 256;
        const int n0 = (wb & 31) * 128;
        const int k0 = (wb >> 5) * 64;
        const int rr = tid >> 4;         // 0..15
        const int cc = (tid & 15) * 8;   // 0..120
#pragma unroll
        for (int p = 0; p < 4; ++p) {
            const int k = p * 16 + rr;
            const float* src = W + (size_t)(k0 + k) * TOTAL + n0 + cc;
            float4 v0 = *(const float4*)src;
            float4 v1 = *(const float4*)(src + 4);
            t[cc][k] = v0.x; t[cc + 1][k] = v0.y; t[cc + 2][k] = v0.z; t[cc + 3][k] = v0.w;
            t[cc + 4][k] = v1.x; t[cc + 5][k] = v1.y; t[cc + 6][k] = v1.z; t[cc + 7][k] = v1.w;
        }
        __syncthreads();
#pragma unroll
        for (int s = tid; s < 1024; s += 256) {
            const int frag = s >> 6;    // 0..15 (4 lrt x 4 lkc)
            const int lane = s & 63;
            const int lrt = frag >> 2;
            const int lkc = frag & 3;
            const int nl = lrt * 32 + (lane & 31);
            const int kl = lkc * 16 + (lane >> 5) * 8;
            float4 f0 = *(const float4*)&t[nl][kl];
            float4 f1 = *(const float4*)&t[nl][kl + 4];
            bf16x8 v;
            v[0] = (__bf16)f0.x; v[1] = (__bf16)f0.y; v[2] = (__bf16)f0.z; v[3] = (__bf16)f0.w;
            v[4] = (__bf16)f1.x; v[5] = (__bf16)f1.y; v[6] = (__bf16)f1.z; v[7] = (__bf16)f1.w;
            const size_t fragG = (size_t)((n0 >> 5) + lrt) * (TOTAL / 16) + ((k0 >> 4) + lkc);
            *(bf16x8*)(WT + fragG * 512 + lane * 8) = v;
        }
    } else {
        swz_slot(out_w, OWT, 1024, NCLS, (bid - 2304) * 256 + tid);
    }
}

// ---- one recurrence step: hn = relu(h @ W + gate*[E,0,0]) (h, hn, WT tiled) ----
// 256 blocks x 1024 thr (16 waves); tile 64m x 64n; 16-way K-split; fold-reduce.
// XCD-aware bid swizzle: all 4 mt of an nt-panel on one XCD.
template <int CHUNKS>
__global__ __launch_bounds__(1024, 4) void k_step(const __bf16* __restrict__ h,
                                                  const __bf16* __restrict__ WT,
                                                  const float* __restrict__ E,
                                                  const int gate,
                                                  __bf16* __restrict__ hn) {
    __shared__ float buf[4][4096];   // 64 KiB
    const int wave = threadIdx.x >> 6;
    const int lane = threadIdx.x & 63;
    const int xcd = blockIdx.x & 7;
    const int idx = blockIdx.x >> 3;       // 0..31
    const int mt = idx & 3;                // m0 = mt*64
    const int nt = xcd * 8 + (idx >> 2);   // 0..63
    constexpr int PER = CHUNKS >> 4;
    const int kc0 = wave * PER;

    const bf16x8* A0 = (const bf16x8*)h  + ((size_t)(mt * 2) * (TOTAL / 16) + kc0) * 64 + lane;
    const bf16x8* A1 = A0 + (size_t)(TOTAL / 16) * 64;
    const bf16x8* B0 = (const bf16x8*)WT + ((size_t)(nt * 2) * (TOTAL / 16) + kc0) * 64 + lane;
    const bf16x8* B1 = B0 + (size_t)(TOTAL / 16) * 64;

    f32x16 ac0 = zero16(), ac1 = zero16(), ac2 = zero16(), ac3 = zero16();
#pragma unroll 4
    for (int i = 0; i < PER; ++i) {
        const int off = i * 64;
        bf16x8 a0 = A0[off];
        bf16x8 a1 = A1[off];
        bf16x8 b0 = B0[off];
        bf16x8 b1 = B1[off];
        ac0 = MFMA(a0, b0, ac0);
        ac1 = MFMA(a0, b1, ac1);
        ac2 = MFMA(a1, b0, ac2);
        ac3 = MFMA(a1, b1, ac3);
    }

    // fold reduce 16 -> 4 partials (layout idx(c,r,l) = (c*16+r)*64 + l):
    // waves 12-15 dump, 8-11 add; 8-11 dump, 4-7 add; 4-7 dump, 0-3 add; 0-3 dump.
    f32x16 accs[4] = {ac0, ac1, ac2, ac3};
#pragma unroll
    for (int hi = 12; hi >= 4; hi -= 4) {
        if (wave >= hi && wave < hi + 4) {
            float* b = buf[wave - hi];
#pragma unroll
            for (int c = 0; c < 4; ++c)
#pragma unroll
                for (int r = 0; r < 16; ++r)
                    b[(c * 16 + r) * 64 + lane] = accs[c][r];
        }
        __syncthreads();
        if (wave >= hi - 4 && wave < hi) {
            const float* b = buf[wave - (hi - 4)];
#pragma unroll
            for (int c = 0; c < 4; ++c)
#pragma unroll
                for (int r = 0; r < 16; ++r)
                    accs[c][r] += b[(c * 16 + r) * 64 + lane];
        }
        __syncthreads();
    }
    if (wave < 4) {
        float* b = buf[wave];
#pragma unroll
        for (int c = 0; c < 4; ++c)
#pragma unroll
            for (int r = 0; r < 16; ++r)
                b[(c * 16 + r) * 64 + lane] = accs[c][r];
    }
    __syncthreads();

    // final 4-way sum + epilogue; 1024 threads x 1 float4
    const int t = threadIdx.x;
    const int c = t >> 8;            // 0..3
    const int r = (t >> 4) & 15;     // 0..15
    const int l0 = (t & 15) * 4;     // 0..60
    const int base = (c * 16 + r) * 64 + l0;
    float4 s = {0.f, 0.f, 0.f, 0.f};
#pragma unroll
    for (int w = 0; w < 4; ++w) {
        float4 v = *(const float4*)&buf[w][base];
        s.x += v.x; s.y += v.y; s.z += v.z; s.w += v.w;
    }
    float v[4] = {s.x, s.y, s.z, s.w};
    const int ih = c >> 1, jh = c & 1;
    const int row = ih * 32 + (r & 3) + 8 * (r >> 2) + 4 * (l0 >> 5);
    const int col0 = jh * 32 + (l0 & 31);
    const int m = mt * 64 + row;
    const int n0g = nt * 64 + col0;
    if (gate && n0g < SDIM) {
        const float* Ep = E + m * SDIM + n0g;
#pragma unroll
        for (int j = 0; j < 4; ++j) v[j] += Ep[j];
    }
    alignas(8) __bf16 o[4];
#pragma unroll
    for (int j = 0; j < 4; ++j) o[j] = (__bf16)fmaxf(v[j], 0.f);
    const size_t frag = (size_t)(m >> 5) * (TOTAL / 16) + (n0g >> 4);
    const int lh = (m & 31) + 32 * ((n0g >> 3) & 1);
    *(ushort4*)(hn + frag * 512 + lh * 8 + (n0g & 7)) = *(const ushort4*)o;
}

// ---- out = h[:, 3072:] @ out_w^T + out_b (h tiled, out_w tiled padded to 1024 rows) ----
__global__ __launch_bounds__(512, 4) void k_out(const __bf16* __restrict__ h,
                                                const __bf16* __restrict__ owt,
                                                const float* __restrict__ out_b,
                                                float* __restrict__ out) {
    __shared__ float red[8][1024];
    const int wave = threadIdx.x >> 6;
    const int lane = threadIdx.x & 63;
    const int mt = blockIdx.x >> 5;
    const int ct = blockIdx.x & 31;
    const int m0 = mt * 32, c0 = ct * 32;
    const int kcA0 = (3072 / 16) + wave * 8;
    const int kcB0 = wave * 8;
    const bf16x8* Ap = (const bf16x8*)h   + ((size_t)mt * (TOTAL / 16) + kcA0) * 64 + lane;
    const bf16x8* Bp = (const bf16x8*)owt + ((size_t)ct * (1024 / 16) + kcB0) * 64 + lane;
    f32x16 acc = zero16();
#pragma unroll
    for (int i = 0; i < 8; ++i)
        acc = MFMA(Ap[i * 64], Bp[i * 64], acc);
#pragma unroll
    for (int r = 0; r < 16; ++r) {
        int row = (r & 3) + 8 * (r >> 2) + 4 * (lane >> 5);
        red[wave][row * 32 + (lane & 31)] = acc[r];
    }
    __syncthreads();
    const int e0 = threadIdx.x * 2;
    float sx = 0.f, sy = 0.f;
#pragma unroll
    for (int w = 0; w < 8; ++w) {
        float2 v = *(const float2*)&red[w][e0];
        sx += v.x; sy += v.y;
    }
    const int row = e0 >> 5, col = e0 & 31;
    const int m = m0 + row;
    const int n = c0 + col;
    if (n < NCLS)     out[m * NCLS + n]     = sx + out_b[n];
    if (n + 1 < NCLS) out[m * NCLS + n + 1] = sy + out_b[n + 1];
}

extern "C" void kernel_launch(void* const* d_in, const int* in_sizes, int n_in,
                              void* d_out, int out_size, void* d_ws, size_t ws_size,
                              hipStream_t stream) {
    const float* x     = (const float*)d_in[0];   // 256 x 2048
    const float* W     = (const float*)d_in[1];   // 4096 x 4096
    const float* in_w  = (const float*)d_in[2];   // 1024 x 2048
    const float* in_b  = (const float*)d_in[3];   // 1024
    const float* out_w = (const float*)d_in[4];   // 1000 x 1024
    const float* out_b = (const float*)d_in[5];   // 1000
    float* out = (float*)d_out;                   // 256 x 1000

    char* ws = (char*)d_ws;
    __bf16* WT  = (__bf16*)(ws + 0);          // 32 MiB  W^T tiled (r=n, c=k)
    __bf16* OWT = (__bf16*)(ws + 33554432);   // 2 MiB   out_w tiled (padded 1024 rows)
    float*  Ebuf= (float*)(ws + 35651584);    // 1 MiB   E f32 row-major
    __bf16* H0  = (__bf16*)(ws + 36700160);   // 2 MiB   h tiled
    __bf16* H1  = (__bf16*)(ws + 38797312);   // 2 MiB   h tiled

    // prep: E-GEMM (writes Ebuf + H0 relu'd) + W transpose-swizzle + out_w swizzle.
    // t=0 collapses to h1 = [relu(E),0,0]; step t=1 reads only K<1024 so H0's upper
    // region needs no memset.
    k_prep<<<2816, 256, 0, stream>>>(W, x, in_w, in_b, out_w, WT, OWT, Ebuf, H0);

    // t = 1..9 (gate fires at t=5); t=1 only needs K=1024
    const __bf16* hs = H0;
    __bf16* hd = H1;
    for (int t = 1; t < 10; ++t) {
        const int gate = (t % 5 == 0) ? 1 : 0;
        if (t == 1)
            k_step<SDIM / 16><<<256, 1024, 0, stream>>>(hs, WT, Ebuf, gate, hd);
        else
            k_step<TOTAL / 16><<<256, 1024, 0, stream>>>(hs, WT, Ebuf, gate, hd);
        const __bf16* tmp = hs; hs = hd; hd = (__bf16*)tmp;
    }

    k_out<<<256, 512, 0, stream>>>(hs, OWT, out_b, out);
}

// Round 10
// 268.868 us; speedup vs baseline: 1.0312x; 1.0312x over previous
//
#include <hip/hip_runtime.h>

// BasicRNN R9: R7 base (best measured) + barrier-free W transpose-swizzle: each lane
// gathers its fragment's 8 f32 elements with row-strided loads (wave-instr = 2x128B
// contiguous segments -> 2 txns), cvt, one 16B store. No LDS, no barriers in the W
// path (R7's 16-round LDS pipeline was issue/barrier-bound at HBM 26%).
// k_step: 512 thr, 64x64 tile, XCD swizzle, plain unroll-4 (R7 exact).
// Fragment-tiled operands:
//   elem(r,c) = frag*512 + lane*8 + (c&7), frag=(r>>5)*(C/16)+(c>>4), lane=(r&31)+32*((c>>3)&1)

typedef __bf16 bf16x8 __attribute__((ext_vector_type(8)));
typedef float  f32x16 __attribute__((ext_vector_type(16)));

#define TOTAL 4096
#define BATCH 256
#define INDIM 2048
#define SDIM  1024
#define NCLS  1000

#define MFMA(a, b, c) __builtin_amdgcn_mfma_f32_32x32x16_bf16((a), (b), (c), 0, 0, 0)

__device__ inline f32x16 zero16() {
    f32x16 v;
#pragma unroll
    for (int i = 0; i < 16; ++i) v[i] = 0.f;
    return v;
}

__device__ inline void swz_slot(const float* __restrict__ in, __bf16* __restrict__ out,
                                int C, int Rvalid, int t) {
    const int lane = t & 63;
    const int frag = t >> 6;
    const int kcN = C >> 4;
    const int rt = frag / kcN;
    const int kc = frag - rt * kcN;
    const int r = rt * 32 + (lane & 31);
    const int c = kc * 16 + (lane >> 5) * 8;
    alignas(16) __bf16 v[8];
    if (r < Rvalid) {
        const float* p = in + (size_t)r * C + c;
#pragma unroll
        for (int j = 0; j < 8; ++j) v[j] = (__bf16)p[j];
    } else {
#pragma unroll
        for (int j = 0; j < 8; ++j) v[j] = (__bf16)0.f;
    }
    *(ulonglong2*)(out + (size_t)t * 8) = *(const ulonglong2*)v;
}

// ---- merged preprocessing + E-GEMM ----
// grid 8960 x 256: [0,256) E-GEMM; [256,8448) W transpose-swizzle (per-lane gather);
//                  [8448,8960) out_w swizzle
__global__ __launch_bounds__(256) void k_prep(const float* __restrict__ W,
                                              const float* __restrict__ x,
                                              const float* __restrict__ in_w,
                                              const float* __restrict__ in_b,
                                              const float* __restrict__ out_w,
                                              __bf16* __restrict__ WT,
                                              __bf16* __restrict__ OWT,
                                              float* __restrict__ Ebuf,
                                              __bf16* __restrict__ H0) {
    __shared__ float red[4][1024];   // E path only (16 KB)
    const int bid = blockIdx.x;
    const int tid = threadIdx.x;
    if (bid < 256) {
        // ---- E = x @ in_w^T + in_b ; H0[:, :1024] = relu(E) (tiled) ----
        const int mt = bid >> 5, nt = bid & 31;
        const int wave = tid >> 6, lane = tid & 63;
        const int l31 = lane & 31, kh = (lane >> 5) * 8;
        const int k0 = wave * 512;
        const float* Ax = x    + (size_t)(mt * 32 + l31) * INDIM + k0 + kh;
        const float* Bw = in_w + (size_t)(nt * 32 + l31) * INDIM + k0 + kh;
        f32x16 acc = zero16();
#pragma unroll 4
        for (int i = 0; i < 32; ++i) {
            const float* pa = Ax + i * 16;
            const float* pb = Bw + i * 16;
            float4 a0 = *(const float4*)pa, a1 = *(const float4*)(pa + 4);
            float4 b0 = *(const float4*)pb, b1 = *(const float4*)(pb + 4);
            bf16x8 a, b;
            a[0] = (__bf16)a0.x; a[1] = (__bf16)a0.y; a[2] = (__bf16)a0.z; a[3] = (__bf16)a0.w;
            a[4] = (__bf16)a1.x; a[5] = (__bf16)a1.y; a[6] = (__bf16)a1.z; a[7] = (__bf16)a1.w;
            b[0] = (__bf16)b0.x; b[1] = (__bf16)b0.y; b[2] = (__bf16)b0.z; b[3] = (__bf16)b0.w;
            b[4] = (__bf16)b1.x; b[5] = (__bf16)b1.y; b[6] = (__bf16)b1.z; b[7] = (__bf16)b1.w;
            acc = MFMA(a, b, acc);
        }
#pragma unroll
        for (int r = 0; r < 16; ++r) {
            int row = (r & 3) + 8 * (r >> 2) + 4 * (lane >> 5);
            red[wave][row * 32 + l31] = acc[r];
        }
        __syncthreads();
        const int e0 = tid * 4;
        float4 s = {0.f, 0.f, 0.f, 0.f};
#pragma unroll
        for (int w = 0; w < 4; ++w) {
            float4 v = *(const float4*)&red[w][e0];
            s.x += v.x; s.y += v.y; s.z += v.z; s.w += v.w;
        }
        const int row = e0 >> 5, col = e0 & 31;
        const int m = mt * 32 + row, n = nt * 32 + col;
        float v[4] = {s.x + in_b[n], s.y + in_b[n + 1], s.z + in_b[n + 2], s.w + in_b[n + 3]};
        *(float4*)(Ebuf + m * SDIM + n) = *(const float4*)v;
        alignas(8) __bf16 o[4];
#pragma unroll
        for (int j = 0; j < 4; ++j) o[j] = (__bf16)fmaxf(v[j], 0.f);
        const size_t frag = (size_t)(m >> 5) * (TOTAL / 16) + (n >> 4);
        const int lh = (m & 31) + 32 * ((n >> 3) & 1);
        *(ushort4*)(H0 + frag * 512 + lh * 8 + (n & 7)) = *(const ushort4*)o;
    } else if (bid < 8448) {
        // ---- W (f32, W[k][n]) -> WT tiled bf16 (r=n, c=k), barrier-free gather ----
        // slot s -> (frag, lane); lane gathers W[k..k+8][n] (8 row-strided f32 loads;
        // per wave-instr: lanes 0-31 = 128B row seg, lanes 32-63 = 128B of row k+8).
        const int s = (bid - 256) * 256 + tid;
        const int lane = s & 63;
        const int frag = s >> 6;                  // 0..32767
        const int rt = frag >> 8;                 // n-tile 0..127 (TOTAL/16 = 256 kc)
        const int kc = frag & 255;
        const int n = rt * 32 + (lane & 31);
        const int k = kc * 16 + (lane >> 5) * 8;
        const float* p = W + (size_t)k * TOTAL + n;
        bf16x8 v;
#pragma unroll
        for (int j = 0; j < 8; ++j) v[j] = (__bf16)p[(size_t)j * TOTAL];
        *(bf16x8*)(WT + (size_t)frag * 512 + lane * 8) = v;
    } else {
        swz_slot(out_w, OWT, 1024, NCLS, (bid - 8448) * 256 + tid);
    }
}

// ---- one recurrence step: hn = relu(h @ W + gate*[E,0,0]) (h, hn, WT tiled) ----
// 256 blocks x 512 thr; block/wave tile 64m x 64n; 8 waves K-split.
// XCD-aware bid swizzle: all 4 mt of an nt-panel on one XCD (bid%8 ~ XCD id).
template <int CHUNKS>
__global__ __launch_bounds__(512, 2) void k_step(const __bf16* __restrict__ h,
                                                 const __bf16* __restrict__ WT,
                                                 const float* __restrict__ E,
                                                 const int gate,
                                                 __bf16* __restrict__ hn) {
    __shared__ float buf[4][4096];   // 64 KiB
    const int wave = threadIdx.x >> 6;
    const int lane = threadIdx.x & 63;
    const int xcd = blockIdx.x & 7;
    const int idx = blockIdx.x >> 3;       // 0..31
    const int mt = idx & 3;                // m0 = mt*64
    const int nt = xcd * 8 + (idx >> 2);   // 0..63
    constexpr int PER = CHUNKS >> 3;
    const int kc0 = wave * PER;

    const bf16x8* A0 = (const bf16x8*)h  + ((size_t)(mt * 2) * (TOTAL / 16) + kc0) * 64 + lane;
    const bf16x8* A1 = A0 + (size_t)(TOTAL / 16) * 64;
    const bf16x8* B0 = (const bf16x8*)WT + ((size_t)(nt * 2) * (TOTAL / 16) + kc0) * 64 + lane;
    const bf16x8* B1 = B0 + (size_t)(TOTAL / 16) * 64;

    f32x16 ac0 = zero16(), ac1 = zero16(), ac2 = zero16(), ac3 = zero16();
#pragma unroll 4
    for (int i = 0; i < PER; ++i) {
        const int off = i * 64;
        bf16x8 a0 = A0[off];
        bf16x8 a1 = A1[off];
        bf16x8 b0 = B0[off];
        bf16x8 b1 = B1[off];
        ac0 = MFMA(a0, b0, ac0);
        ac1 = MFMA(a0, b1, ac1);
        ac2 = MFMA(a1, b0, ac2);
        ac3 = MFMA(a1, b1, ac3);
    }

    // two-phase reduce: idx(c,r,l) = (c*16+r)*64 + l (2-way bank alias: free)
    f32x16 accs[4] = {ac0, ac1, ac2, ac3};
    if (wave >= 4) {
        float* b = buf[wave - 4];
#pragma unroll
        for (int c = 0; c < 4; ++c)
#pragma unroll
            for (int r = 0; r < 16; ++r)
                b[(c * 16 + r) * 64 + lane] = accs[c][r];
    }
    __syncthreads();
    if (wave < 4) {
        float* b = buf[wave];
#pragma unroll
        for (int c = 0; c < 4; ++c)
#pragma unroll
            for (int r = 0; r < 16; ++r) {
                const int i2 = (c * 16 + r) * 64 + lane;
                b[i2] += accs[c][r];
            }
    }
    __syncthreads();

    // final 4-way sum + epilogue; thread t -> (c, r, 8 lanes from l0)
    const int t = threadIdx.x;
    const int c = t >> 7;            // 0..3
    const int r = (t >> 3) & 15;     // 0..15
    const int l0 = (t & 7) * 8;      // 0..56
    const int base = (c * 16 + r) * 64 + l0;
    float4 s0 = {0.f, 0.f, 0.f, 0.f}, s1 = {0.f, 0.f, 0.f, 0.f};
#pragma unroll
    for (int w = 0; w < 4; ++w) {
        const float4* p = (const float4*)&buf[w][base];
        float4 v0 = p[0], v1 = p[1];
        s0.x += v0.x; s0.y += v0.y; s0.z += v0.z; s0.w += v0.w;
        s1.x += v1.x; s1.y += v1.y; s1.z += v1.z; s1.w += v1.w;
    }
    float v[8] = {s0.x, s0.y, s0.z, s0.w, s1.x, s1.y, s1.z, s1.w};
    const int ih = c >> 1, jh = c & 1;
    const int row = ih * 32 + (r & 3) + 8 * (r >> 2) + 4 * (l0 >> 5);
    const int col0 = jh * 32 + (l0 & 31);
    const int m = mt * 64 + row;
    const int n0g = nt * 64 + col0;
    if (gate && n0g < SDIM) {
        const float* Ep = E + m * SDIM + n0g;
#pragma unroll
        for (int j = 0; j < 8; ++j) v[j] += Ep[j];
    }
    alignas(16) __bf16 o[8];
#pragma unroll
    for (int j = 0; j < 8; ++j) o[j] = (__bf16)fmaxf(v[j], 0.f);
    const size_t frag = (size_t)(m >> 5) * (TOTAL / 16) + (n0g >> 4);
    const int lh = (m & 31) + 32 * ((n0g >> 3) & 1);
    *(ulonglong2*)(hn + frag * 512 + lh * 8) = *(const ulonglong2*)o;
}

// ---- out = h[:, 3072:] @ out_w^T + out_b (h tiled, out_w tiled padded to 1024 rows) ----
__global__ __launch_bounds__(512, 4) void k_out(const __bf16* __restrict__ h,
                                                const __bf16* __restrict__ owt,
                                                const float* __restrict__ out_b,
                                                float* __restrict__ out) {
    __shared__ float red[8][1024];
    const int wave = threadIdx.x >> 6;
    const int lane = threadIdx.x & 63;
    const int mt = blockIdx.x >> 5;
    const int ct = blockIdx.x & 31;
    const int m0 = mt * 32, c0 = ct * 32;
    const int kcA0 = (3072 / 16) + wave * 8;
    const int kcB0 = wave * 8;
    const bf16x8* Ap = (const bf16x8*)h   + ((size_t)mt * (TOTAL / 16) + kcA0) * 64 + lane;
    const bf16x8* Bp = (const bf16x8*)owt + ((size_t)ct * (1024 / 16) + kcB0) * 64 + lane;
    f32x16 acc = zero16();
#pragma unroll
    for (int i = 0; i < 8; ++i)
        acc = MFMA(Ap[i * 64], Bp[i * 64], acc);
#pragma unroll
    for (int r = 0; r < 16; ++r) {
        int row = (r & 3) + 8 * (r >> 2) + 4 * (lane >> 5);
        red[wave][row * 32 + (lane & 31)] = acc[r];
    }
    __syncthreads();
    const int e0 = threadIdx.x * 2;
    float sx = 0.f, sy = 0.f;
#pragma unroll
    for (int w = 0; w < 8; ++w) {
        float2 v = *(const float2*)&red[w][e0];
        sx += v.x; sy += v.y;
    }
    const int row = e0 >> 5, col = e0 & 31;
    const int m = m0 + row;
    const int n = c0 + col;
    if (n < NCLS)     out[m * NCLS + n]     = sx + out_b[n];
    if (n + 1 < NCLS) out[m * NCLS + n + 1] = sy + out_b[n + 1];
}

extern "C" void kernel_launch(void* const* d_in, const int* in_sizes, int n_in,
                              void* d_out, int out_size, void* d_ws, size_t ws_size,
                              hipStream_t stream) {
    const float* x     = (const float*)d_in[0];   // 256 x 2048
    const float* W     = (const float*)d_in[1];   // 4096 x 4096
    const float* in_w  = (const float*)d_in[2];   // 1024 x 2048
    const float* in_b  = (const float*)d_in[3];   // 1024
    const float* out_w = (const float*)d_in[4];   // 1000 x 1024
    const float* out_b = (const float*)d_in[5];   // 1000
    float* out = (float*)d_out;                   // 256 x 1000

    char* ws = (char*)d_ws;
    __bf16* WT  = (__bf16*)(ws + 0);          // 32 MiB  W^T tiled (r=n, c=k)
    __bf16* OWT = (__bf16*)(ws + 33554432);   // 2 MiB   out_w tiled (padded 1024 rows)
    float*  Ebuf= (float*)(ws + 35651584);    // 1 MiB   E f32 row-major
    __bf16* H0  = (__bf16*)(ws + 36700160);   // 2 MiB   h tiled
    __bf16* H1  = (__bf16*)(ws + 38797312);   // 2 MiB   h tiled

    // prep: E-GEMM (writes Ebuf + H0 relu'd) + W transpose-swizzle + out_w swizzle.
    // t=0 collapses to h1 = [relu(E),0,0]; step t=1 reads only K<1024 so H0's upper
    // region needs no memset.
    k_prep<<<8960, 256, 0, stream>>>(W, x, in_w, in_b, out_w, WT, OWT, Ebuf, H0);

    // t = 1..9 (gate fires at t=5); t=1 only needs K=1024
    const __bf16* hs = H0;
    __bf16* hd = H1;
    for (int t = 1; t < 10; ++t) {
        const int gate = (t % 5 == 0) ? 1 : 0;
        if (t == 1)
            k_step<SDIM / 16><<<256, 512, 0, stream>>>(hs, WT, Ebuf, gate, hd);
        else
            k_step<TOTAL / 16><<<256, 512, 0, stream>>>(hs, WT, Ebuf, gate, hd);
        const __bf16* tmp = hs; hs = hd; hd = (__bf16*)tmp;
    }

    k_out<<<256, 512, 0, stream>>>(hs, OWT, out_b, out);
}

// Round 11
// 263.610 us; speedup vs baseline: 1.0518x; 1.0199x over previous
//
#include <hip/hip_runtime.h>

// BasicRNN R10: k_prep W-phase rebuilt around DRAM row-buffer locality — R7/R8/R9 all
// read W in <=512B row fragments and all plateaued at ~1.9TB/s / 40-44us. Now each
// block stages a 16k x 512n tile: reads are 2KB contiguous per W row (streaming),
// LDS t[16][512] written as stride-1 float4 (conflict-free b128), frag gather is 8x
// ds_read_b32 at bank=lane&31 (2-way alias = free). k_step/k_out = R7 exact (best).
// Fragment-tiled operands:
//   elem(r,c) = frag*512 + lane*8 + (c&7), frag=(r>>5)*(C/16)+(c>>4), lane=(r&31)+32*((c>>3)&1)

typedef __bf16 bf16x8 __attribute__((ext_vector_type(8)));
typedef float  f32x16 __attribute__((ext_vector_type(16)));

#define TOTAL 4096
#define BATCH 256
#define INDIM 2048
#define SDIM  1024
#define NCLS  1000

#define MFMA(a, b, c) __builtin_amdgcn_mfma_f32_32x32x16_bf16((a), (b), (c), 0, 0, 0)

__device__ inline f32x16 zero16() {
    f32x16 v;
#pragma unroll
    for (int i = 0; i < 16; ++i) v[i] = 0.f;
    return v;
}

__device__ inline void swz_slot(const float* __restrict__ in, __bf16* __restrict__ out,
                                int C, int Rvalid, int t) {
    const int lane = t & 63;
    const int frag = t >> 6;
    const int kcN = C >> 4;
    const int rt = frag / kcN;
    const int kc = frag - rt * kcN;
    const int r = rt * 32 + (lane & 31);
    const int c = kc * 16 + (lane >> 5) * 8;
    alignas(16) __bf16 v[8];
    if (r < Rvalid) {
        const float* p = in + (size_t)r * C + c;
#pragma unroll
        for (int j = 0; j < 8; ++j) v[j] = (__bf16)p[j];
    } else {
#pragma unroll
        for (int j = 0; j < 8; ++j) v[j] = (__bf16)0.f;
    }
    *(ulonglong2*)(out + (size_t)t * 8) = *(const ulonglong2*)v;
}

// ---- merged preprocessing + E-GEMM ----
// grid 2816 x 256: [0,256) E-GEMM; [256,2304) W transpose-swizzle (16k x 512n tiles);
//                  [2304,2816) out_w swizzle
__global__ __launch_bounds__(256) void k_prep(const float* __restrict__ W,
                                              const float* __restrict__ x,
                                              const float* __restrict__ in_w,
                                              const float* __restrict__ in_b,
                                              const float* __restrict__ out_w,
                                              __bf16* __restrict__ WT,
                                              __bf16* __restrict__ OWT,
                                              float* __restrict__ Ebuf,
                                              __bf16* __restrict__ H0) {
    __shared__ float t[16 * 512];   // 32 KB; E path reuses first 4x1024 as reduce buf
    const int bid = blockIdx.x;
    const int tid = threadIdx.x;
    if (bid < 256) {
        // ---- E = x @ in_w^T + in_b ; H0[:, :1024] = relu(E) (tiled) ----
        float* red = t;   // 4 x 1024
        const int mt = bid >> 5, nt = bid & 31;
        const int wave = tid >> 6, lane = tid & 63;
        const int l31 = lane & 31, kh = (lane >> 5) * 8;
        const int k0 = wave * 512;
        const float* Ax = x    + (size_t)(mt * 32 + l31) * INDIM + k0 + kh;
        const float* Bw = in_w + (size_t)(nt * 32 + l31) * INDIM + k0 + kh;
        f32x16 acc = zero16();
#pragma unroll 4
        for (int i = 0; i < 32; ++i) {
            const float* pa = Ax + i * 16;
            const float* pb = Bw + i * 16;
            float4 a0 = *(const float4*)pa, a1 = *(const float4*)(pa + 4);
            float4 b0 = *(const float4*)pb, b1 = *(const float4*)(pb + 4);
            bf16x8 a, b;
            a[0] = (__bf16)a0.x; a[1] = (__bf16)a0.y; a[2] = (__bf16)a0.z; a[3] = (__bf16)a0.w;
            a[4] = (__bf16)a1.x; a[5] = (__bf16)a1.y; a[6] = (__bf16)a1.z; a[7] = (__bf16)a1.w;
            b[0] = (__bf16)b0.x; b[1] = (__bf16)b0.y; b[2] = (__bf16)b0.z; b[3] = (__bf16)b0.w;
            b[4] = (__bf16)b1.x; b[5] = (__bf16)b1.y; b[6] = (__bf16)b1.z; b[7] = (__bf16)b1.w;
            acc = MFMA(a, b, acc);
        }
#pragma unroll
        for (int r = 0; r < 16; ++r) {
            int row = (r & 3) + 8 * (r >> 2) + 4 * (lane >> 5);
            red[wave * 1024 + row * 32 + l31] = acc[r];
        }
        __syncthreads();
        const int e0 = tid * 4;
        float4 s = {0.f, 0.f, 0.f, 0.f};
#pragma unroll
        for (int w = 0; w < 4; ++w) {
            float4 v = *(const float4*)&red[w * 1024 + e0];
            s.x += v.x; s.y += v.y; s.z += v.z; s.w += v.w;
        }
        const int row = e0 >> 5, col = e0 & 31;
        const int m = mt * 32 + row, n = nt * 32 + col;
        float v[4] = {s.x + in_b[n], s.y + in_b[n + 1], s.z + in_b[n + 2], s.w + in_b[n + 3]};
        *(float4*)(Ebuf + m * SDIM + n) = *(const float4*)v;
        alignas(8) __bf16 o[4];
#pragma unroll
        for (int j = 0; j < 4; ++j) o[j] = (__bf16)fmaxf(v[j], 0.f);
        const size_t frag = (size_t)(m >> 5) * (TOTAL / 16) + (n >> 4);
        const int lh = (m & 31) + 32 * ((n >> 3) & 1);
        *(ushort4*)(H0 + frag * 512 + lh * 8 + (n & 7)) = *(const ushort4*)o;
    } else if (bid < 2304) {
        // ---- W (f32, W[k][n]) -> WT tiled bf16 (r=n, c=k); 16k x 512n tile ----
        const int wb = bid - 256;
        const int k0 = (wb >> 3) * 16;     // 256 k-tiles
        const int n0 = (wb & 7) * 512;     // 8 n-panels
        // stage: 16 rows x 2KB contiguous reads -> t[k][n], float4 LDS writes
#pragma unroll
        for (int i = 0; i < 8; ++i) {
            const int slot = i * 256 + tid;        // 2048 float4 slots
            const int row = slot >> 7;             // 128 float4 per row
            const int c4 = (slot & 127) * 4;
            float4 v = *(const float4*)(W + (size_t)(k0 + row) * TOTAL + n0 + c4);
            *(float4*)&t[row * 512 + c4] = v;
        }
        __syncthreads();
        // emit: 16 frags (rt_local 0..15) at fixed kc; 8x ds_read_b32 column gather
        const int kcG = k0 >> 4;
#pragma unroll
        for (int s = tid; s < 1024; s += 256) {
            const int rtl = s >> 6;
            const int lane = s & 63;
            const int nl = rtl * 32 + (lane & 31);
            const int kl = (lane >> 5) * 8;
            bf16x8 v;
#pragma unroll
            for (int j = 0; j < 8; ++j) v[j] = (__bf16)t[(kl + j) * 512 + nl];
            const size_t fragG = (size_t)((n0 >> 5) + rtl) * (TOTAL / 16) + kcG;
            *(bf16x8*)(WT + fragG * 512 + lane * 8) = v;
        }
    } else {
        swz_slot(out_w, OWT, 1024, NCLS, (bid - 2304) * 256 + tid);
    }
}

// ---- one recurrence step: hn = relu(h @ W + gate*[E,0,0]) (h, hn, WT tiled) ----
// 256 blocks x 512 thr; block/wave tile 64m x 64n; 8 waves K-split.
// XCD-aware bid swizzle: all 4 mt of an nt-panel on one XCD (bid%8 ~ XCD id).
template <int CHUNKS>
__global__ __launch_bounds__(512, 2) void k_step(const __bf16* __restrict__ h,
                                                 const __bf16* __restrict__ WT,
                                                 const float* __restrict__ E,
                                                 const int gate,
                                                 __bf16* __restrict__ hn) {
    __shared__ float buf[4][4096];   // 64 KiB
    const int wave = threadIdx.x >> 6;
    const int lane = threadIdx.x & 63;
    const int xcd = blockIdx.x & 7;
    const int idx = blockIdx.x >> 3;       // 0..31
    const int mt = idx & 3;                // m0 = mt*64
    const int nt = xcd * 8 + (idx >> 2);   // 0..63
    constexpr int PER = CHUNKS >> 3;
    const int kc0 = wave * PER;

    const bf16x8* A0 = (const bf16x8*)h  + ((size_t)(mt * 2) * (TOTAL / 16) + kc0) * 64 + lane;
    const bf16x8* A1 = A0 + (size_t)(TOTAL / 16) * 64;
    const bf16x8* B0 = (const bf16x8*)WT + ((size_t)(nt * 2) * (TOTAL / 16) + kc0) * 64 + lane;
    const bf16x8* B1 = B0 + (size_t)(TOTAL / 16) * 64;

    f32x16 ac0 = zero16(), ac1 = zero16(), ac2 = zero16(), ac3 = zero16();
#pragma unroll 4
    for (int i = 0; i < PER; ++i) {
        const int off = i * 64;
        bf16x8 a0 = A0[off];
        bf16x8 a1 = A1[off];
        bf16x8 b0 = B0[off];
        bf16x8 b1 = B1[off];
        ac0 = MFMA(a0, b0, ac0);
        ac1 = MFMA(a0, b1, ac1);
        ac2 = MFMA(a1, b0, ac2);
        ac3 = MFMA(a1, b1, ac3);
    }

    // two-phase reduce: idx(c,r,l) = (c*16+r)*64 + l (2-way bank alias: free)
    f32x16 accs[4] = {ac0, ac1, ac2, ac3};
    if (wave >= 4) {
        float* b = buf[wave - 4];
#pragma unroll
        for (int c = 0; c < 4; ++c)
#pragma unroll
            for (int r = 0; r < 16; ++r)
                b[(c * 16 + r) * 64 + lane] = accs[c][r];
    }
    __syncthreads();
    if (wave < 4) {
        float* b = buf[wave];
#pragma unroll
        for (int c = 0; c < 4; ++c)
#pragma unroll
            for (int r = 0; r < 16; ++r) {
                const int i2 = (c * 16 + r) * 64 + lane;
                b[i2] += accs[c][r];
            }
    }
    __syncthreads();

    // final 4-way sum + epilogue; thread t -> (c, r, 8 lanes from l0)
    const int t = threadIdx.x;
    const int c = t >> 7;            // 0..3
    const int r = (t >> 3) & 15;     // 0..15
    const int l0 = (t & 7) * 8;      // 0..56
    const int base = (c * 16 + r) * 64 + l0;
    float4 s0 = {0.f, 0.f, 0.f, 0.f}, s1 = {0.f, 0.f, 0.f, 0.f};
#pragma unroll
    for (int w = 0; w < 4; ++w) {
        const float4* p = (const float4*)&buf[w][base];
        float4 v0 = p[0], v1 = p[1];
        s0.x += v0.x; s0.y += v0.y; s0.z += v0.z; s0.w += v0.w;
        s1.x += v1.x; s1.y += v1.y; s1.z += v1.z; s1.w += v1.w;
    }
    float v[8] = {s0.x, s0.y, s0.z, s0.w, s1.x, s1.y, s1.z, s1.w};
    const int ih = c >> 1, jh = c & 1;
    const int row = ih * 32 + (r & 3) + 8 * (r >> 2) + 4 * (l0 >> 5);
    const int col0 = jh * 32 + (l0 & 31);
    const int m = mt * 64 + row;
    const int n0g = nt * 64 + col0;
    if (gate && n0g < SDIM) {
        const float* Ep = E + m * SDIM + n0g;
#pragma unroll
        for (int j = 0; j < 8; ++j) v[j] += Ep[j];
    }
    alignas(16) __bf16 o[8];
#pragma unroll
    for (int j = 0; j < 8; ++j) o[j] = (__bf16)fmaxf(v[j], 0.f);
    const size_t frag = (size_t)(m >> 5) * (TOTAL / 16) + (n0g >> 4);
    const int lh = (m & 31) + 32 * ((n0g >> 3) & 1);
    *(ulonglong2*)(hn + frag * 512 + lh * 8) = *(const ulonglong2*)o;
}

// ---- out = h[:, 3072:] @ out_w^T + out_b (h tiled, out_w tiled padded to 1024 rows) ----
__global__ __launch_bounds__(512, 4) void k_out(const __bf16* __restrict__ h,
                                                const __bf16* __restrict__ owt,
                                                const float* __restrict__ out_b,
                                                float* __restrict__ out) {
    __shared__ float red[8][1024];
    const int wave = threadIdx.x >> 6;
    const int lane = threadIdx.x & 63;
    const int mt = blockIdx.x >> 5;
    const int ct = blockIdx.x & 31;
    const int m0 = mt * 32, c0 = ct * 32;
    const int kcA0 = (3072 / 16) + wave * 8;
    const int kcB0 = wave * 8;
    const bf16x8* Ap = (const bf16x8*)h   + ((size_t)mt * (TOTAL / 16) + kcA0) * 64 + lane;
    const bf16x8* Bp = (const bf16x8*)owt + ((size_t)ct * (1024 / 16) + kcB0) * 64 + lane;
    f32x16 acc = zero16();
#pragma unroll
    for (int i = 0; i < 8; ++i)
        acc = MFMA(Ap[i * 64], Bp[i * 64], acc);
#pragma unroll
    for (int r = 0; r < 16; ++r) {
        int row = (r & 3) + 8 * (r >> 2) + 4 * (lane >> 5);
        red[wave][row * 32 + (lane & 31)] = acc[r];
    }
    __syncthreads();
    const int e0 = threadIdx.x * 2;
    float sx = 0.f, sy = 0.f;
#pragma unroll
    for (int w = 0; w < 8; ++w) {
        float2 v = *(const float2*)&red[w][e0];
        sx += v.x; sy += v.y;
    }
    const int row = e0 >> 5, col = e0 & 31;
    const int m = m0 + row;
    const int n = c0 + col;
    if (n < NCLS)     out[m * NCLS + n]     = sx + out_b[n];
    if (n + 1 < NCLS) out[m * NCLS + n + 1] = sy + out_b[n + 1];
}

extern "C" void kernel_launch(void* const* d_in, const int* in_sizes, int n_in,
                              void* d_out, int out_size, void* d_ws, size_t ws_size,
                              hipStream_t stream) {
    const float* x     = (const float*)d_in[0];   // 256 x 2048
    const float* W     = (const float*)d_in[1];   // 4096 x 4096
    const float* in_w  = (const float*)d_in[2];   // 1024 x 2048
    const float* in_b  = (const float*)d_in[3];   // 1024
    const float* out_w = (const float*)d_in[4];   // 1000 x 1024
    const float* out_b = (const float*)d_in[5];   // 1000
    float* out = (float*)d_out;                   // 256 x 1000

    char* ws = (char*)d_ws;
    __bf16* WT  = (__bf16*)(ws + 0);          // 32 MiB  W^T tiled (r=n, c=k)
    __bf16* OWT = (__bf16*)(ws + 33554432);   // 2 MiB   out_w tiled (padded 1024 rows)
    float*  Ebuf= (float*)(ws + 35651584);    // 1 MiB   E f32 row-major
    __bf16* H0  = (__bf16*)(ws + 36700160);   // 2 MiB   h tiled
    __bf16* H1  = (__bf16*)(ws + 38797312);   // 2 MiB   h tiled

    // prep: E-GEMM (writes Ebuf + H0 relu'd) + W transpose-swizzle + out_w swizzle.
    // t=0 collapses to h1 = [relu(E),0,0]; step t=1 reads only K<1024 so H0's upper
    // region needs no memset.
    k_prep<<<2816, 256, 0, stream>>>(W, x, in_w, in_b, out_w, WT, OWT, Ebuf, H0);

    // t = 1..9 (gate fires at t=5); t=1 only needs K=1024
    const __bf16* hs = H0;
    __bf16* hd = H1;
    for (int t = 1; t < 10; ++t) {
        const int gate = (t % 5 == 0) ? 1 : 0;
        if (t == 1)
            k_step<SDIM / 16><<<256, 512, 0, stream>>>(hs, WT, Ebuf, gate, hd);
        else
            k_step<TOTAL / 16><<<256, 512, 0, stream>>>(hs, WT, Ebuf, gate, hd);
        const __bf16* tmp = hs; hs = hd; hd = (__bf16*)tmp;
    }

    k_out<<<256, 512, 0, stream>>>(hs, OWT, out_b, out);
}